// Round 13
// baseline (343.444 us; speedup 1.0000x reference)
//
#include <hip/hip_runtime.h>
#include <hip/hip_bf16.h>
#include <math.h>

// ---------------- sizes ----------------
#define NN1   10000
#define NE    160000
#define FIN   256
#define HID   500
#define K1    5000
#define NN2   5000
#define K2    2500

// ---------------- ws layout (float offsets) ----------------
#define CSR_OFFS   0u
#define CSR_POS    10008u
#define CSR_EDGE   20008u                   // 160000 int2 -> pad 340016
#define OFF_AGG    340016u                  // bf16 agg (ushort)
#define OFF_H      2900016u                 // h bf16 [10000,500]
#define OFF_XP2    (OFF_H + 2500000u)       // xp2 bf16 [2500,500]
#define OFF_SCP    7900016u                 // scpart [16][10000] fp32 (ends 8,060,016)
#define OFF_KEY    8100016u                 // 10000 u64 keys (20000 floats)
#define OFF_SC     8150016u                 // 10000 fp32 summed scores
#define OFF_RK1    10410016u
#define OFF_Z      10432016u
#define OFF_T1     10433016u
#define OFF_T2     10435016u
#define OFF_INV    10439016u
#define OFF_CNT    10439024u                // cntp[<=10][10000] ints
#define OFF_PM1    10639024u
#define OFF_PS1    10671024u
#define OFF_XB     10703024u
#define OFF_W1RB   11983024u
#define OFF_W1TB   12047024u
#define OFF_W2RB   12111024u
#define OFF_W2TB   12236024u
#define OFF_XP1B   12361024u
#define OFF_PM2    13611024u
#define OFF_PS2    13627024u
#define WS_FLOATS  13643024u

#define RCHUNK 1000
#define ROSLAB1 64
#define ROSLAB2 32
#define RORPB   79

// prep grid partition (1024 elems per convert block)
#define PB_S1 2500   // x (2,560,000)
#define PB_S2 2625   // +125 w1r
#define PB_S3 2750   // +125 w1t
#define PB_S4 2995   // +245 w2r
#define PB_S5 3240   // +245 w2t
#define PB_S6 3242   // +2 norms
#define PB_S7 3867   // +625 hist

// ---------------- helpers ----------------
__device__ inline unsigned f2ord(float f) {
    unsigned u = __float_as_uint(f);
    return (u & 0x80000000u) ? ~u : (u | 0x80000000u);
}
__device__ inline unsigned long long rkey(float s, int j) {
    return ((unsigned long long)f2ord(s) << 32) | (unsigned)(0xFFFFFFFFu - (unsigned)j);
}
__device__ inline unsigned short bf16rn(float f) {
    unsigned u = __float_as_uint(f);
    u += 0x7FFFu + ((u >> 16) & 1u);
    return (unsigned short)(u >> 16);
}
__device__ inline float bf2f(unsigned short u) {
    return __uint_as_float((unsigned)u << 16);
}

typedef __attribute__((ext_vector_type(8))) short short8;
typedef __attribute__((ext_vector_type(4))) float floatx4;

// ---------------- kernels ----------------

// fused prep, flattened 1-D grid: [0,S1) x-cvt, [S1,S2) w1r, [S2,S3) w1t,
// [S3,S4) w2r, [S4,S5) w2t, [S5,S6) norms, [S6,S7) hist
__global__ __launch_bounds__(256) void k_prep(
    const float* __restrict__ x, unsigned short* __restrict__ xb,
    const float* __restrict__ w1r, unsigned short* __restrict__ w1rb,
    const float* __restrict__ w1t, unsigned short* __restrict__ w1tb,
    const float* __restrict__ w2r, unsigned short* __restrict__ w2rb,
    const float* __restrict__ w2t, unsigned short* __restrict__ w2tb,
    const float* __restrict__ p1, const float* __restrict__ p2,
    float* __restrict__ invn,
    const int* __restrict__ edst, int* __restrict__ pos) {
    __shared__ float red[256];
    int b = blockIdx.x;
    if (b < PB_S5) {
        const float* s; unsigned short* d; int n; int lb;
        if (b < PB_S1)      { s = x;   d = xb;   n = NN1 * FIN; lb = b; }
        else if (b < PB_S2) { s = w1r; d = w1rb; n = HID * FIN; lb = b - PB_S1; }
        else if (b < PB_S3) { s = w1t; d = w1tb; n = HID * FIN; lb = b - PB_S2; }
        else if (b < PB_S4) { s = w2r; d = w2rb; n = HID * HID; lb = b - PB_S3; }
        else                { s = w2t; d = w2tb; n = HID * HID; lb = b - PB_S4; }
        int i = (lb * 256 + threadIdx.x) * 4;
        if (i >= n) return;
        if (i + 3 < n) {
            float4 v = *(const float4*)(s + i);
            ushort4 o;
            o.x = bf16rn(v.x); o.y = bf16rn(v.y); o.z = bf16rn(v.z); o.w = bf16rn(v.w);
            *(ushort4*)(d + i) = o;
        } else {
            for (int q = 0; q < 4 && i + q < n; ++q) d[i + q] = bf16rn(s[i + q]);
        }
    } else if (b < PB_S6) {
        const float* p = (b - PB_S5) ? p2 : p1;
        float s = 0.f;
        for (int i = threadIdx.x; i < HID; i += 256) { float v = p[i]; s += v * v; }
        red[threadIdx.x] = s; __syncthreads();
        for (int w = 128; w > 0; w >>= 1) {
            if (threadIdx.x < w) red[threadIdx.x] += red[threadIdx.x + w];
            __syncthreads();
        }
        if (threadIdx.x == 0) invn[b - PB_S5] = 1.0f / sqrtf(red[0]);
    } else {
        int e = (b - PB_S6) * 256 + threadIdx.x;
        if (e < NE) atomicAdd(&pos[edst[e]], 1);
    }
}

// single-block exclusive scan; writes offs[0..NN1] AND pos working copy
__global__ __launch_bounds__(1024) void k_scan(int* __restrict__ pos, int* __restrict__ offs) {
    __shared__ int tot[1024];
    int t = threadIdx.x;
    int base = t * 10;
    int loc[10]; int s = 0;
    #pragma unroll
    for (int q = 0; q < 10; ++q) {
        int v = (base + q < NN1) ? pos[base + q] : 0;
        loc[q] = s; s += v;
    }
    tot[t] = s; __syncthreads();
    for (int d = 1; d < 1024; d <<= 1) {
        int v = (t >= d) ? tot[t - d] : 0;
        __syncthreads();
        tot[t] += v;
        __syncthreads();
    }
    int excl = (t == 0) ? 0 : tot[t - 1];
    #pragma unroll
    for (int q = 0; q < 10; ++q)
        if (base + q < NN1) { int o = excl + loc[q]; offs[base + q] = o; pos[base + q] = o; }
    if (t == 1023) offs[NN1] = tot[1023];
}

// fill packed edges: one 8B store per edge
__global__ void k_fill(const int* __restrict__ src, const int* __restrict__ dst,
                       const float* __restrict__ w, int* __restrict__ pos,
                       int2* __restrict__ ce) {
    int e = blockIdx.x * 256 + threadIdx.x;
    if (e >= NE) return;
    int slot = atomicAdd(&pos[dst[e]], 1);
    ce[slot] = make_int2(src[e], __float_as_int(w[e]));
}

// conv1 aggregation, 2-edge unroll with dual accumulator chains
__global__ __launch_bounds__(256) void k_gather1(
    const unsigned short* __restrict__ xb, const int* __restrict__ offs,
    const int2* __restrict__ ce, unsigned short* __restrict__ aggb) {
    int wave = (blockIdx.x * 256 + threadIdx.x) >> 6;
    int lane = threadIdx.x & 63;
    if (wave >= NN1) return;
    int b = offs[wave], e = offs[wave + 1];
    float4 a0 = make_float4(0.f, 0.f, 0.f, 0.f);
    float4 a1 = make_float4(0.f, 0.f, 0.f, 0.f);
    int p = b;
    for (; p + 1 < e; p += 2) {
        int2 e0 = ce[p], e1 = ce[p + 1];
        float w0 = __int_as_float(e0.y), w1 = __int_as_float(e1.y);
        ushort4 u0 = *(const ushort4*)(xb + (size_t)e0.x * FIN + lane * 4);
        ushort4 u1 = *(const ushort4*)(xb + (size_t)e1.x * FIN + lane * 4);
        a0.x += bf2f(u0.x) * w0; a0.y += bf2f(u0.y) * w0;
        a0.z += bf2f(u0.z) * w0; a0.w += bf2f(u0.w) * w0;
        a1.x += bf2f(u1.x) * w1; a1.y += bf2f(u1.y) * w1;
        a1.z += bf2f(u1.z) * w1; a1.w += bf2f(u1.w) * w1;
    }
    if (p < e) {
        int2 e0 = ce[p];
        float w0 = __int_as_float(e0.y);
        ushort4 u0 = *(const ushort4*)(xb + (size_t)e0.x * FIN + lane * 4);
        a0.x += bf2f(u0.x) * w0; a0.y += bf2f(u0.y) * w0;
        a0.z += bf2f(u0.z) * w0; a0.w += bf2f(u0.w) * w0;
    }
    ushort4 o;
    o.x = bf16rn(a0.x + a1.x); o.y = bf16rn(a0.y + a1.y);
    o.z = bf16rn(a0.z + a1.z); o.w = bf16rn(a0.w + a1.w);
    *(ushort4*)(aggb + (size_t)wave * FIN + lane * 4) = o;
}

// conv2 aggregation from bf16 xp1 (rank-filtered) -> bf16 agg
__global__ __launch_bounds__(256) void k_gather2(
    const unsigned short* __restrict__ Xb, const int* __restrict__ offs,
    const int2* __restrict__ ce, const int* __restrict__ rank,
    unsigned short* __restrict__ aggb) {
    int wave = (blockIdx.x * 256 + threadIdx.x) >> 6;
    int lane = threadIdx.x & 63;
    if (wave >= NN1) return;
    int rd = rank[wave];
    if (rd < 0) return;
    int b = offs[wave], e = offs[wave + 1];
    int c1 = 256 + lane * 4;
    float a0 = 0.f, a1 = 0.f, a2 = 0.f, a3 = 0.f;
    float b0 = 0.f, b1v = 0.f, b2 = 0.f, b3 = 0.f;
    int2 nxt = (b < e) ? ce[b] : make_int2(0, 0);
    for (int p = b; p < e; ++p) {
        int2 cur = nxt;
        if (p + 1 < e) nxt = ce[p + 1];
        int rs = rank[cur.x];
        if (rs < 0) continue;
        float we = __int_as_float(cur.y);
        const unsigned short* row = Xb + (size_t)rs * HID;
        ushort4 u = *(const ushort4*)(row + lane * 4);
        a0 += bf2f(u.x) * we; a1 += bf2f(u.y) * we;
        a2 += bf2f(u.z) * we; a3 += bf2f(u.w) * we;
        if (c1 < HID) {
            ushort4 u2 = *(const ushort4*)(row + c1);
            b0 += bf2f(u2.x) * we; b1v += bf2f(u2.y) * we;
            b2 += bf2f(u2.z) * we; b3 += bf2f(u2.w) * we;
        }
    }
    unsigned short* o = aggb + (size_t)rd * HID;
    ushort4 o1; o1.x = bf16rn(a0); o1.y = bf16rn(a1); o1.z = bf16rn(a2); o1.w = bf16rn(a3);
    *(ushort4*)(o + lane * 4) = o1;
    if (c1 < HID) {
        ushort4 o2; o2.x = bf16rn(b0); o2.y = bf16rn(b1v); o2.z = bf16rn(b2); o2.w = bf16rn(b3);
        *(ushort4*)(o + c1) = o2;
    }
}

// guarded 16B bf16 load
__device__ inline short8 ld8g(const unsigned short* p, int gk, int K) {
    if (gk + 7 < K) return *(const short8*)p;
    unsigned short tmp[8] = {0,0,0,0,0,0,0,0};
    for (int q = 0; q < 8; ++q) if (gk + q < K) tmp[q] = p[q];
    return *(short8*)tmp;
}

// ---- bf16 MFMA GEMM: XOR-swizzled LDS, double-buffered, 2-deep prefetch ----
#define GBK 64
__global__ __launch_bounds__(256) void k_gemm_bf16(
    const unsigned short* __restrict__ A1, const unsigned short* __restrict__ B1,
    const unsigned short* __restrict__ A2, const unsigned short* __restrict__ B2,
    const float* __restrict__ bias, const float* __restrict__ pv,
    unsigned short* __restrict__ C, float* __restrict__ scpart,
    int M, int N, int Ka, int Kb, int nbyRow) {
    int b = blockIdx.x;
    int xcd = b & 7, seq = b >> 3;
    int colT = seq & 7;
    int rowT = xcd + 8 * (seq >> 3);
    if (rowT >= nbyRow) return;
    int row0 = rowT * 64, col0 = colT * 64;

    __shared__ unsigned short As[2][64 * 64];
    __shared__ unsigned short Bs[2][64 * 64];
    int tid = threadIdx.x;
    int lane = tid & 63, wid = tid >> 6;
    int waveM = wid & 1, waveN = wid >> 1;
    int quad = lane >> 4, mrow = lane & 15;
    int m7 = mrow & 7;
    floatx4 acc[2][2] = {};

    int sr = tid >> 2;
    int ca = (tid & 3) * 2;
    int s7 = sr & 7;
    int c0 = (ca ^ s7) * 8;
    int c1 = ((ca + 1) ^ s7) * 8;
    int sbase = sr * 64;

    int nka = (Ka + GBK - 1) / GBK;
    int nkb = (Kb + GBK - 1) / GBK;
    int niter = nka + nkb;

    short8 z8 = {0,0,0,0,0,0,0,0};
    short8 paA = z8, paB = z8, pbA = z8, pbB = z8;

    auto fetch = [&](int t) {
        int ph = (t >= nka);
        const unsigned short* A = ph ? A2 : A1;
        const unsigned short* B = ph ? B2 : B1;
        int K = ph ? Kb : Ka;
        int gk = (ph ? t - nka : t) * GBK + ca * 8;
        int gr = row0 + sr, gn = col0 + sr;
        paA = z8; paB = z8; pbA = z8; pbB = z8;
        if (gr < M) {
            const unsigned short* p = A + (size_t)gr * K + gk;
            paA = ld8g(p, gk, K); paB = ld8g(p + 8, gk + 8, K);
        }
        if (gn < N) {
            const unsigned short* p = B + (size_t)gn * K + gk;
            pbA = ld8g(p, gk, K); pbB = ld8g(p + 8, gk + 8, K);
        }
    };
    auto commit = [&](int buf) {
        *(short8*)&As[buf][sbase + c0] = paA;
        *(short8*)&As[buf][sbase + c1] = paB;
        *(short8*)&Bs[buf][sbase + c0] = pbA;
        *(short8*)&Bs[buf][sbase + c1] = pbB;
    };

    fetch(0);
    commit(0);
    if (niter > 1) fetch(1);
    __syncthreads();

    for (int it = 0; it < niter; ++it) {
        int cur = it & 1;
        if (it + 1 < niter) commit(cur ^ 1);
        if (it + 2 < niter) fetch(it + 2);
        #pragma unroll
        for (int half = 0; half < 2; ++half) {
            int qc = half * 4 + quad;
            int qoff = (qc ^ m7) * 8;
            short8 bfr[2];
            #pragma unroll
            for (int nt = 0; nt < 2; ++nt)
                bfr[nt] = *(short8*)&Bs[cur][(waveN * 32 + nt * 16 + mrow) * 64 + qoff];
            #pragma unroll
            for (int mt = 0; mt < 2; ++mt) {
                short8 afr = *(short8*)&As[cur][(waveM * 32 + mt * 16 + mrow) * 64 + qoff];
                #pragma unroll
                for (int nt = 0; nt < 2; ++nt)
                    acc[mt][nt] = __builtin_amdgcn_mfma_f32_16x16x32_bf16(
                        afr, bfr[nt], acc[mt][nt], 0, 0, 0);
            }
        }
        __syncthreads();
    }
    float ps[2][4] = {};
    #pragma unroll
    for (int nt = 0; nt < 2; ++nt) {
        int col = col0 + waveN * 32 + nt * 16 + mrow;
        if (col >= N) continue;
        float bv = bias[col];
        float pc = pv[col];
        #pragma unroll
        for (int mt = 0; mt < 2; ++mt) {
            int rbase = row0 + waveM * 32 + mt * 16 + quad * 4;
            #pragma unroll
            for (int r = 0; r < 4; ++r) {
                float v = fmaxf(acc[mt][nt][r] + bv, 0.f);
                int row = rbase + r;
                if (row < M) C[(size_t)row * N + col] = bf16rn(v);
                ps[mt][r] += v * pc;
            }
        }
    }
    int part = colT * 2 + waveN;
    #pragma unroll
    for (int mt = 0; mt < 2; ++mt)
        #pragma unroll
        for (int r = 0; r < 4; ++r) {
            float v = ps[mt][r];
            v += __shfl_xor(v, 1, 64); v += __shfl_xor(v, 2, 64);
            v += __shfl_xor(v, 4, 64); v += __shfl_xor(v, 8, 64);
            if (mrow == 0) {
                int row = row0 + waveM * 32 + mt * 16 + quad * 4 + r;
                if (row < M) scpart[(size_t)part * M + row] = v;
            }
        }
}

// sum 16 score partials -> sc[i]; emit sortable key[i]
__global__ __launch_bounds__(256) void k_scsum(
    const float* __restrict__ scpart, float* __restrict__ sc,
    unsigned long long* __restrict__ key, int Nn) {
    int i = blockIdx.x * 256 + threadIdx.x;
    if (i >= Nn) return;
    float s = 0.f;
    #pragma unroll
    for (int q = 0; q < 16; ++q) s += scpart[(size_t)q * Nn + i];
    sc[i] = s;
    key[i] = rkey(s, i);
}

// rank partial counts from prebuilt keys -> cntp[chunk][i]
__global__ __launch_bounds__(256) void k_rank_partial(
    const unsigned long long* __restrict__ key, int* __restrict__ cntp, int Nn) {
    __shared__ unsigned long long kj[RCHUNK];
    int j0 = blockIdx.y * RCHUNK;
    int jn = min(Nn - j0, RCHUNK);
    for (int t = threadIdx.x; t < jn; t += 256)
        kj[t] = key[j0 + t];
    __syncthreads();
    int i = blockIdx.x * 256 + threadIdx.x;
    if (i >= Nn) return;
    unsigned long long ki = key[i];
    int c = 0;
    #pragma unroll 4
    for (int q = 0; q < jn; ++q)
        c += (kj[q] > ki) ? 1 : 0;
    cntp[(size_t)blockIdx.y * Nn + i] = c;
}

// pool gather, wave-per-node: rank finalize (shfl) + tanh + bf16 row scatter
__global__ __launch_bounds__(256) void k_gather_pool(
    const unsigned short* __restrict__ Hb, const float* __restrict__ sc,
    const float* __restrict__ invn,
    const int* __restrict__ cntp, int Nn, int nchunk, int kk,
    int* __restrict__ rank_out, unsigned short* __restrict__ Xb) {
    int wave = (blockIdx.x * 256 + threadIdx.x) >> 6;
    int lane = threadIdx.x & 63;
    if (wave >= Nn) return;
    int i = wave;
    int c = (lane < nchunk) ? cntp[(size_t)lane * Nn + i] : 0;
    #pragma unroll
    for (int off = 8; off > 0; off >>= 1) c += __shfl_down(c, off, 64);
    c = __shfl(c, 0, 64);
    int r = (c < kk) ? c : -1;
    if (lane == 0 && rank_out) rank_out[i] = r;
    if (r < 0) return;
    float s = tanhf(sc[i] * invn[0]);
    for (int cc = lane; cc < HID / 4; cc += 64) {
        ushort4 u = *(const ushort4*)(Hb + (size_t)i * HID + cc * 4);
        ushort4 o;
        o.x = bf16rn(bf2f(u.x) * s); o.y = bf16rn(bf2f(u.y) * s);
        o.z = bf16rn(bf2f(u.z) * s); o.w = bf16rn(bf2f(u.w) * s);
        *(ushort4*)(Xb + (size_t)r * HID + cc * 4) = o;
    }
}

// readout phase A over bf16 rows: per-slab column max+sum, no atomics
__global__ __launch_bounds__(256) void k_readout_slab(
    const unsigned short* __restrict__ X, int rows, int rpb,
    float* __restrict__ pmax, float* __restrict__ psum) {
    __shared__ float4 lmx[4][64];
    __shared__ float4 lsm[4][64];
    int lane = threadIdx.x & 63;
    int rgrp = threadIdx.x >> 6;
    int c4 = blockIdx.x * 64 + lane;
    int r0 = blockIdx.y * rpb;
    int r1 = min(rows, r0 + rpb);
    float4 mx = make_float4(-INFINITY, -INFINITY, -INFINITY, -INFINITY);
    float4 sm = make_float4(0.f, 0.f, 0.f, 0.f);
    if (c4 < HID / 4) {
        for (int r = r0 + rgrp; r < r1; r += 4) {
            ushort4 u = *(const ushort4*)(X + (size_t)r * HID + c4 * 4);
            float vx = bf2f(u.x), vy = bf2f(u.y), vz = bf2f(u.z), vw = bf2f(u.w);
            mx.x = fmaxf(mx.x, vx); mx.y = fmaxf(mx.y, vy);
            mx.z = fmaxf(mx.z, vz); mx.w = fmaxf(mx.w, vw);
            sm.x += vx; sm.y += vy; sm.z += vz; sm.w += vw;
        }
    }
    lmx[rgrp][lane] = mx; lsm[rgrp][lane] = sm;
    __syncthreads();
    if (rgrp == 0 && c4 < HID / 4) {
        #pragma unroll
        for (int g = 1; g < 4; ++g) {
            float4 m2 = lmx[g][lane], s2 = lsm[g][lane];
            mx.x = fmaxf(mx.x, m2.x); mx.y = fmaxf(mx.y, m2.y);
            mx.z = fmaxf(mx.z, m2.z); mx.w = fmaxf(mx.w, m2.w);
            sm.x += s2.x; sm.y += s2.y; sm.z += s2.z; sm.w += s2.w;
        }
        *(float4*)(pmax + (size_t)blockIdx.y * HID + c4 * 4) = mx;
        *(float4*)(psum + (size_t)blockIdx.y * HID + c4 * 4) = sm;
    }
}

// fold both pools' slabs -> z[1000]
__global__ __launch_bounds__(64) void k_combine_all(
    const float* __restrict__ pm1, const float* __restrict__ ps1, int ns1,
    const float* __restrict__ pm2, const float* __restrict__ ps2, int ns2,
    float* __restrict__ z) {
    int j = blockIdx.x * 64 + threadIdx.x;
    if (j >= HID) return;
    float m1 = -INFINITY, s1 = 0.f;
    for (int s = 0; s < ns1; ++s) {
        m1 = fmaxf(m1, pm1[(size_t)s * HID + j]);
        s1 += ps1[(size_t)s * HID + j];
    }
    float m2 = -INFINITY, s2 = 0.f;
    for (int s = 0; s < ns2; ++s) {
        m2 = fmaxf(m2, pm2[(size_t)s * HID + j]);
        s2 += ps2[(size_t)s * HID + j];
    }
    z[j] = m1 + m2;
    z[HID + j] = s1 * (1.0f / (float)K1) + s2 * (1.0f / (float)K2);
}

__global__ __launch_bounds__(256) void k_mv(
    const float* __restrict__ v, const float* __restrict__ W,
    const float* __restrict__ bias, float* __restrict__ y,
    int rowsN, int K, int act) {
    int wave = (blockIdx.x * 256 + threadIdx.x) >> 6;
    int lane = threadIdx.x & 63;
    if (wave >= rowsN) return;
    const float* wr = W + (size_t)wave * K;
    float s = 0.f;
    for (int c = lane * 4; c < K; c += 256) {
        float4 a = *(const float4*)(wr + c);
        float4 xv = *(const float4*)(v + c);
        s += a.x * xv.x + a.y * xv.y + a.z * xv.z + a.w * xv.w;
    }
    for (int off = 32; off > 0; off >>= 1) s += __shfl_down(s, off, 64);
    if (lane == 0) {
        float r = s + bias[wave];
        y[wave] = (act == 0) ? fmaxf(r, 0.f) : 1.f / (1.f + expf(-r));
    }
}

// ---------------- launch ----------------
extern "C" void kernel_launch(void* const* d_in, const int* in_sizes, int n_in,
                              void* d_out, int out_size, void* d_ws, size_t ws_size,
                              hipStream_t stream) {
    const float* x      = (const float*)d_in[0];
    const int*   esrc   = (const int*)d_in[1];
    const int*   edst   = (const int*)d_in[2];
    const float* ew     = (const float*)d_in[3];
    const float* W1_rel = (const float*)d_in[4];
    const float* b1     = (const float*)d_in[5];
    const float* W1_root= (const float*)d_in[6];
    const float* p1     = (const float*)d_in[7];
    const float* W2_rel = (const float*)d_in[8];
    const float* b2     = (const float*)d_in[9];
    const float* W2_root= (const float*)d_in[10];
    const float* p2     = (const float*)d_in[11];
    const float* l1W    = (const float*)d_in[12];
    const float* l1b    = (const float*)d_in[13];
    const float* l2W    = (const float*)d_in[14];
    const float* l2b    = (const float*)d_in[15];
    const float* l3W    = (const float*)d_in[16];
    const float* l3b    = (const float*)d_in[17];
    float* out = (float*)d_out;
    float* ws  = (float*)d_ws;

    if (ws_size < (size_t)WS_FLOATS * sizeof(float)) return;

    int*                offs  = (int*)(ws + CSR_OFFS);
    int*                pos   = (int*)(ws + CSR_POS);
    int2*               ce    = (int2*)(ws + CSR_EDGE);
    unsigned short*     aggb  = (unsigned short*)(ws + OFF_AGG);
    unsigned short*     hb    = (unsigned short*)(ws + OFF_H);
    unsigned short*     xp2b  = (unsigned short*)(ws + OFF_XP2);
    float*              scp   = ws + OFF_SCP;
    unsigned long long* key   = (unsigned long long*)(ws + OFF_KEY);
    float*              sc    = ws + OFF_SC;
    int*                rk1   = (int*)(ws + OFF_RK1);
    float*              zbuf  = ws + OFF_Z;
    float*              t1    = ws + OFF_T1;
    float*              t2    = ws + OFF_T2;
    float*              invn  = ws + OFF_INV;
    int*                cntp  = (int*)(ws + OFF_CNT);
    float*              pm1   = ws + OFF_PM1;
    float*              ps1   = ws + OFF_PS1;
    float*              pm2   = ws + OFF_PM2;
    float*              ps2   = ws + OFF_PS2;
    unsigned short*     xb    = (unsigned short*)(ws + OFF_XB);
    unsigned short*     w1rb  = (unsigned short*)(ws + OFF_W1RB);
    unsigned short*     w1tb  = (unsigned short*)(ws + OFF_W1TB);
    unsigned short*     w2rb  = (unsigned short*)(ws + OFF_W2RB);
    unsigned short*     w2tb  = (unsigned short*)(ws + OFF_W2TB);
    unsigned short*     xp1b  = (unsigned short*)(ws + OFF_XP1B);

    hipMemsetAsync(pos, 0, NN1 * sizeof(int), stream);
    k_prep<<<PB_S7, 256, 0, stream>>>(
        x, xb, W1_rel, w1rb, W1_root, w1tb, W2_rel, w2rb, W2_root, w2tb,
        p1, p2, invn, edst, pos);
    k_scan<<<1, 1024, 0, stream>>>(pos, offs);
    k_fill<<<(NE + 255) / 256, 256, 0, stream>>>(esrc, edst, ew, pos, ce);

    // conv1 (+fused score partials vs p1)
    k_gather1<<<(NN1 * 64 + 255) / 256, 256, 0, stream>>>(xb, offs, ce, aggb);
    {
        int nby = (NN1 + 63) / 64;
        int nblk = 64 * ((nby + 7) / 8);
        k_gemm_bf16<<<nblk, 256, 0, stream>>>(
            aggb, w1rb, xb, w1tb, b1, p1, hb, scp, NN1, HID, FIN, FIN, nby);
    }

    // pool1
    k_scsum<<<(NN1 + 255) / 256, 256, 0, stream>>>(scp, sc, key, NN1);
    k_rank_partial<<<dim3((NN1 + 255) / 256, NN1 / RCHUNK), 256, 0, stream>>>(key, cntp, NN1);
    k_gather_pool<<<(NN1 * 64 + 255) / 256, 256, 0, stream>>>(
        hb, sc, invn + 0, cntp, NN1, NN1 / RCHUNK, K1, rk1, xp1b);
    k_readout_slab<<<dim3(2, ROSLAB1), 256, 0, stream>>>(xp1b, K1, RORPB, pm1, ps1);

    // conv2 (+fused score partials vs p2)
    k_gather2<<<(NN1 * 64 + 255) / 256, 256, 0, stream>>>(xp1b, offs, ce, rk1, aggb);
    {
        int nby = (NN2 + 63) / 64;
        int nblk = 64 * ((nby + 7) / 8);
        k_gemm_bf16<<<nblk, 256, 0, stream>>>(
            aggb, w2rb, xp1b, w2tb, b2, p2, hb, scp, NN2, HID, HID, HID, nby);
    }

    // pool2 + combine
    k_scsum<<<(NN2 + 255) / 256, 256, 0, stream>>>(scp, sc, key, NN2);
    k_rank_partial<<<dim3((NN2 + 255) / 256, NN2 / RCHUNK), 256, 0, stream>>>(key, cntp, NN2);
    k_gather_pool<<<(NN2 * 64 + 255) / 256, 256, 0, stream>>>(
        hb, sc, invn + 1, cntp, NN2, NN2 / RCHUNK, K2, (int*)nullptr, xp2b);
    k_readout_slab<<<dim3(2, ROSLAB2), 256, 0, stream>>>(xp2b, K2, RORPB, pm2, ps2);
    k_combine_all<<<(HID + 63) / 64, 64, 0, stream>>>(pm1, ps1, ROSLAB1, pm2, ps2, ROSLAB2, zbuf);

    // MLP
    k_mv<<<(2000 * 64) / 256, 256, 0, stream>>>(zbuf, l1W, l1b, t1, 2000, 1000, 0);
    k_mv<<<(4000 * 64) / 256, 256, 0, stream>>>(t1, l2W, l2b, t2, 4000, 2000, 0);
    k_mv<<<(100 * 64) / 256, 256, 0, stream>>>(t2, l3W, l3b, out, 100, 4000, 1);
}

// Round 14
// 328.718 us; speedup vs baseline: 1.0448x; 1.0448x over previous
//
#include <hip/hip_runtime.h>
#include <hip/hip_bf16.h>
#include <math.h>

// ---------------- sizes ----------------
#define NN1   10000
#define NE    160000
#define FIN   256
#define HID   500
#define K1    5000
#define NN2   5000
#define K2    2500

// ---------------- ws layout (float offsets) ----------------
#define CSR_OFFS   0u
#define CSR_POS    10008u
#define CSR_EDGE   20008u                   // 160000 int2 -> pad 340016
#define OFF_AGG    340016u                  // bf16 agg (ushort)
#define OFF_H      2900016u                 // h bf16 [10000,500]
#define OFF_XP2    (OFF_H + 2500000u)       // xp2 bf16 [2500,500]
#define OFF_SCP    7900016u                 // scpart [16][10000] fp32
#define OFF_RK1    10410016u
#define OFF_Z      10432016u
#define OFF_T1     10433016u
#define OFF_T2     10435016u
#define OFF_INV    10439016u
#define OFF_CNT    10439024u                // 200000 ints
#define OFF_PM1    10639024u
#define OFF_PS1    10671024u
#define OFF_XB     10703024u
#define OFF_W1RB   11983024u
#define OFF_W1TB   12047024u
#define OFF_W2RB   12111024u
#define OFF_W2TB   12236024u
#define OFF_XP1B   12361024u
#define OFF_PM2    13611024u
#define OFF_PS2    13627024u
#define WS_FLOATS  13643024u

#define RCHUNK 500
#define ROSLAB1 64
#define ROSLAB2 32
#define RORPB   79

// ---------------- helpers ----------------
__device__ inline unsigned f2ord(float f) {
    unsigned u = __float_as_uint(f);
    return (u & 0x80000000u) ? ~u : (u | 0x80000000u);
}
__device__ inline unsigned long long rkey(float s, int j) {
    return ((unsigned long long)f2ord(s) << 32) | (unsigned)(0xFFFFFFFFu - (unsigned)j);
}
__device__ inline unsigned short bf16rn(float f) {
    unsigned u = __float_as_uint(f);
    u += 0x7FFFu + ((u >> 16) & 1u);
    return (unsigned short)(u >> 16);
}
__device__ inline float bf2f(unsigned short u) {
    return __uint_as_float((unsigned)u << 16);
}

typedef __attribute__((ext_vector_type(8))) short short8;
typedef __attribute__((ext_vector_type(4))) float floatx4;

// ---------------- kernels ----------------

// fused prep: y<5 -> fp32->bf16 convert; y==5 -> p-norms; y==6 -> degree hist
__global__ __launch_bounds__(256) void k_prep(
    const float* __restrict__ x, unsigned short* __restrict__ xb,
    const float* __restrict__ w1r, unsigned short* __restrict__ w1rb,
    const float* __restrict__ w1t, unsigned short* __restrict__ w1tb,
    const float* __restrict__ w2r, unsigned short* __restrict__ w2rb,
    const float* __restrict__ w2t, unsigned short* __restrict__ w2tb,
    const float* __restrict__ p1, const float* __restrict__ p2,
    float* __restrict__ invn,
    const int* __restrict__ edst, int* __restrict__ pos) {
    __shared__ float red[256];
    int y = blockIdx.y;
    if (y < 5) {
        const float* s; unsigned short* d; int n;
        switch (y) {
            case 0: s = x;   d = xb;   n = NN1 * FIN; break;
            case 1: s = w1r; d = w1rb; n = HID * FIN; break;
            case 2: s = w1t; d = w1tb; n = HID * FIN; break;
            case 3: s = w2r; d = w2rb; n = HID * HID; break;
            default: s = w2t; d = w2tb; n = HID * HID; break;
        }
        int i = (blockIdx.x * 256 + threadIdx.x) * 4;
        if (i >= n) return;
        if (i + 3 < n) {
            float4 v = *(const float4*)(s + i);
            ushort4 o;
            o.x = bf16rn(v.x); o.y = bf16rn(v.y); o.z = bf16rn(v.z); o.w = bf16rn(v.w);
            *(ushort4*)(d + i) = o;
        } else {
            for (int q = 0; q < 4 && i + q < n; ++q) d[i + q] = bf16rn(s[i + q]);
        }
    } else if (y == 5) {
        if (blockIdx.x >= 2) return;
        const float* p = blockIdx.x ? p2 : p1;
        float s = 0.f;
        for (int i = threadIdx.x; i < HID; i += 256) { float v = p[i]; s += v * v; }
        red[threadIdx.x] = s; __syncthreads();
        for (int w = 128; w > 0; w >>= 1) {
            if (threadIdx.x < w) red[threadIdx.x] += red[threadIdx.x + w];
            __syncthreads();
        }
        if (threadIdx.x == 0) invn[blockIdx.x] = 1.0f / sqrtf(red[0]);
    } else {
        int e = blockIdx.x * 256 + threadIdx.x;
        if (e < NE) atomicAdd(&pos[edst[e]], 1);
    }
}

// single-block exclusive scan; writes offs[0..NN1] AND pos working copy
__global__ __launch_bounds__(1024) void k_scan(int* __restrict__ pos, int* __restrict__ offs) {
    __shared__ int tot[1024];
    int t = threadIdx.x;
    int base = t * 10;
    int loc[10]; int s = 0;
    #pragma unroll
    for (int q = 0; q < 10; ++q) {
        int v = (base + q < NN1) ? pos[base + q] : 0;
        loc[q] = s; s += v;
    }
    tot[t] = s; __syncthreads();
    for (int d = 1; d < 1024; d <<= 1) {
        int v = (t >= d) ? tot[t - d] : 0;
        __syncthreads();
        tot[t] += v;
        __syncthreads();
    }
    int excl = (t == 0) ? 0 : tot[t - 1];
    #pragma unroll
    for (int q = 0; q < 10; ++q)
        if (base + q < NN1) { int o = excl + loc[q]; offs[base + q] = o; pos[base + q] = o; }
    if (t == 1023) offs[NN1] = tot[1023];
}

// fill packed edges: one 8B store per edge
__global__ void k_fill(const int* __restrict__ src, const int* __restrict__ dst,
                       const float* __restrict__ w, int* __restrict__ pos,
                       int2* __restrict__ ce) {
    int e = blockIdx.x * 256 + threadIdx.x;
    if (e >= NE) return;
    int slot = atomicAdd(&pos[dst[e]], 1);
    ce[slot] = make_int2(src[e], __float_as_int(w[e]));
}

// conv1 aggregation, 2-edge unroll with dual accumulator chains
__global__ __launch_bounds__(256) void k_gather1(
    const unsigned short* __restrict__ xb, const int* __restrict__ offs,
    const int2* __restrict__ ce, unsigned short* __restrict__ aggb) {
    int wave = (blockIdx.x * 256 + threadIdx.x) >> 6;
    int lane = threadIdx.x & 63;
    if (wave >= NN1) return;
    int b = offs[wave], e = offs[wave + 1];
    float4 a0 = make_float4(0.f, 0.f, 0.f, 0.f);
    float4 a1 = make_float4(0.f, 0.f, 0.f, 0.f);
    int p = b;
    for (; p + 1 < e; p += 2) {
        int2 e0 = ce[p], e1 = ce[p + 1];
        float w0 = __int_as_float(e0.y), w1 = __int_as_float(e1.y);
        ushort4 u0 = *(const ushort4*)(xb + (size_t)e0.x * FIN + lane * 4);
        ushort4 u1 = *(const ushort4*)(xb + (size_t)e1.x * FIN + lane * 4);
        a0.x += bf2f(u0.x) * w0; a0.y += bf2f(u0.y) * w0;
        a0.z += bf2f(u0.z) * w0; a0.w += bf2f(u0.w) * w0;
        a1.x += bf2f(u1.x) * w1; a1.y += bf2f(u1.y) * w1;
        a1.z += bf2f(u1.z) * w1; a1.w += bf2f(u1.w) * w1;
    }
    if (p < e) {
        int2 e0 = ce[p];
        float w0 = __int_as_float(e0.y);
        ushort4 u0 = *(const ushort4*)(xb + (size_t)e0.x * FIN + lane * 4);
        a0.x += bf2f(u0.x) * w0; a0.y += bf2f(u0.y) * w0;
        a0.z += bf2f(u0.z) * w0; a0.w += bf2f(u0.w) * w0;
    }
    ushort4 o;
    o.x = bf16rn(a0.x + a1.x); o.y = bf16rn(a0.y + a1.y);
    o.z = bf16rn(a0.z + a1.z); o.w = bf16rn(a0.w + a1.w);
    *(ushort4*)(aggb + (size_t)wave * FIN + lane * 4) = o;
}

// conv2 aggregation from bf16 xp1 (rank-filtered) -> bf16 agg
__global__ __launch_bounds__(256) void k_gather2(
    const unsigned short* __restrict__ Xb, const int* __restrict__ offs,
    const int2* __restrict__ ce, const int* __restrict__ rank,
    unsigned short* __restrict__ aggb) {
    int wave = (blockIdx.x * 256 + threadIdx.x) >> 6;
    int lane = threadIdx.x & 63;
    if (wave >= NN1) return;
    int rd = rank[wave];
    if (rd < 0) return;
    int b = offs[wave], e = offs[wave + 1];
    int c1 = 256 + lane * 4;
    float a0 = 0.f, a1 = 0.f, a2 = 0.f, a3 = 0.f;
    float b0 = 0.f, b1v = 0.f, b2 = 0.f, b3 = 0.f;
    int2 nxt = (b < e) ? ce[b] : make_int2(0, 0);
    for (int p = b; p < e; ++p) {
        int2 cur = nxt;
        if (p + 1 < e) nxt = ce[p + 1];
        int rs = rank[cur.x];
        if (rs < 0) continue;
        float we = __int_as_float(cur.y);
        const unsigned short* row = Xb + (size_t)rs * HID;
        ushort4 u = *(const ushort4*)(row + lane * 4);
        a0 += bf2f(u.x) * we; a1 += bf2f(u.y) * we;
        a2 += bf2f(u.z) * we; a3 += bf2f(u.w) * we;
        if (c1 < HID) {
            ushort4 u2 = *(const ushort4*)(row + c1);
            b0 += bf2f(u2.x) * we; b1v += bf2f(u2.y) * we;
            b2 += bf2f(u2.z) * we; b3 += bf2f(u2.w) * we;
        }
    }
    unsigned short* o = aggb + (size_t)rd * HID;
    ushort4 o1; o1.x = bf16rn(a0); o1.y = bf16rn(a1); o1.z = bf16rn(a2); o1.w = bf16rn(a3);
    *(ushort4*)(o + lane * 4) = o1;
    if (c1 < HID) {
        ushort4 o2; o2.x = bf16rn(b0); o2.y = bf16rn(b1v); o2.z = bf16rn(b2); o2.w = bf16rn(b3);
        *(ushort4*)(o + c1) = o2;
    }
}

// guarded 16B bf16 load
__device__ inline short8 ld8g(const unsigned short* p, int gk, int K) {
    if (gk + 7 < K) return *(const short8*)p;
    unsigned short tmp[8] = {0,0,0,0,0,0,0,0};
    for (int q = 0; q < 8; ++q) if (gk + q < K) tmp[q] = p[q];
    return *(short8*)tmp;
}

// ---- bf16 MFMA GEMM: XOR-swizzled LDS, double-buffered, 2-deep prefetch ----
// C(bf16) = relu(A1@B1^T + A2@B2^T + bias); fused score partials vs pv.
#define GBK 64
__global__ __launch_bounds__(256) void k_gemm_bf16(
    const unsigned short* __restrict__ A1, const unsigned short* __restrict__ B1,
    const unsigned short* __restrict__ A2, const unsigned short* __restrict__ B2,
    const float* __restrict__ bias, const float* __restrict__ pv,
    unsigned short* __restrict__ C, float* __restrict__ scpart,
    int M, int N, int Ka, int Kb, int nbyRow) {
    int b = blockIdx.x;
    int xcd = b & 7, seq = b >> 3;
    int colT = seq & 7;
    int rowT = xcd + 8 * (seq >> 3);
    if (rowT >= nbyRow) return;
    int row0 = rowT * 64, col0 = colT * 64;

    __shared__ unsigned short As[2][64 * 64];
    __shared__ unsigned short Bs[2][64 * 64];
    int tid = threadIdx.x;
    int lane = tid & 63, wid = tid >> 6;
    int waveM = wid & 1, waveN = wid >> 1;
    int quad = lane >> 4, mrow = lane & 15;
    int m7 = mrow & 7;
    floatx4 acc[2][2] = {};

    int sr = tid >> 2;              // staging row 0..63
    int ca = (tid & 3) * 2;         // chunk pair base (0,2,4,6)
    int s7 = sr & 7;
    int c0 = (ca ^ s7) * 8;         // swizzled ushort offsets
    int c1 = ((ca + 1) ^ s7) * 8;
    int sbase = sr * 64;

    int nka = (Ka + GBK - 1) / GBK;
    int nkb = (Kb + GBK - 1) / GBK;
    int niter = nka + nkb;

    short8 z8 = {0,0,0,0,0,0,0,0};
    short8 paA = z8, paB = z8, pbA = z8, pbB = z8;

    auto fetch = [&](int t) {
        int ph = (t >= nka);
        const unsigned short* A = ph ? A2 : A1;
        const unsigned short* B = ph ? B2 : B1;
        int K = ph ? Kb : Ka;
        int gk = (ph ? t - nka : t) * GBK + ca * 8;
        int gr = row0 + sr, gn = col0 + sr;
        paA = z8; paB = z8; pbA = z8; pbB = z8;
        if (gr < M) {
            const unsigned short* p = A + (size_t)gr * K + gk;
            paA = ld8g(p, gk, K); paB = ld8g(p + 8, gk + 8, K);
        }
        if (gn < N) {
            const unsigned short* p = B + (size_t)gn * K + gk;
            pbA = ld8g(p, gk, K); pbB = ld8g(p + 8, gk + 8, K);
        }
    };
    auto commit = [&](int buf) {
        *(short8*)&As[buf][sbase + c0] = paA;
        *(short8*)&As[buf][sbase + c1] = paB;
        *(short8*)&Bs[buf][sbase + c0] = pbA;
        *(short8*)&Bs[buf][sbase + c1] = pbB;
    };

    fetch(0);
    commit(0);
    if (niter > 1) fetch(1);
    __syncthreads();

    for (int it = 0; it < niter; ++it) {
        int cur = it & 1;
        if (it + 1 < niter) commit(cur ^ 1);
        if (it + 2 < niter) fetch(it + 2);
        #pragma unroll
        for (int half = 0; half < 2; ++half) {
            int qc = half * 4 + quad;           // chunk index
            int qoff = (qc ^ m7) * 8;           // swizzled ushort offset
            short8 bfr[2];
            #pragma unroll
            for (int nt = 0; nt < 2; ++nt)
                bfr[nt] = *(short8*)&Bs[cur][(waveN * 32 + nt * 16 + mrow) * 64 + qoff];
            #pragma unroll
            for (int mt = 0; mt < 2; ++mt) {
                short8 afr = *(short8*)&As[cur][(waveM * 32 + mt * 16 + mrow) * 64 + qoff];
                #pragma unroll
                for (int nt = 0; nt < 2; ++nt)
                    acc[mt][nt] = __builtin_amdgcn_mfma_f32_16x16x32_bf16(
                        afr, bfr[nt], acc[mt][nt], 0, 0, 0);
            }
        }
        __syncthreads();
    }
    // epilogue: bias + relu -> bf16 C; fused score partials
    float ps[2][4] = {};
    #pragma unroll
    for (int nt = 0; nt < 2; ++nt) {
        int col = col0 + waveN * 32 + nt * 16 + mrow;
        if (col >= N) continue;
        float bv = bias[col];
        float pc = pv[col];
        #pragma unroll
        for (int mt = 0; mt < 2; ++mt) {
            int rbase = row0 + waveM * 32 + mt * 16 + quad * 4;
            #pragma unroll
            for (int r = 0; r < 4; ++r) {
                float v = fmaxf(acc[mt][nt][r] + bv, 0.f);
                int row = rbase + r;
                if (row < M) C[(size_t)row * N + col] = bf16rn(v);
                ps[mt][r] += v * pc;
            }
        }
    }
    int part = colT * 2 + waveN;
    #pragma unroll
    for (int mt = 0; mt < 2; ++mt)
        #pragma unroll
        for (int r = 0; r < 4; ++r) {
            float v = ps[mt][r];
            v += __shfl_xor(v, 1, 64); v += __shfl_xor(v, 2, 64);
            v += __shfl_xor(v, 4, 64); v += __shfl_xor(v, 8, 64);
            if (mrow == 0) {
                int row = row0 + waveM * 32 + mt * 16 + quad * 4 + r;
                if (row < M) scpart[(size_t)part * M + row] = v;
            }
        }
}

// rank partial counts from score partials -> cntp[chunk][i]
__global__ __launch_bounds__(256) void k_rank_partial(
    const float* __restrict__ scpart, int* __restrict__ cntp, int Nn) {
    __shared__ unsigned long long kj[RCHUNK];
    int j0 = blockIdx.y * RCHUNK;
    int jn = min(Nn - j0, RCHUNK);
    for (int t = threadIdx.x; t < jn; t += 256) {
        float s = 0.f;
        #pragma unroll
        for (int q = 0; q < 16; ++q) s += scpart[(size_t)q * Nn + j0 + t];
        kj[t] = rkey(s, j0 + t);
    }
    __syncthreads();
    int i = blockIdx.x * 256 + threadIdx.x;
    if (i >= Nn) return;
    float si = 0.f;
    #pragma unroll
    for (int q = 0; q < 16; ++q) si += scpart[(size_t)q * Nn + i];
    unsigned long long ki = rkey(si, i);
    int c = 0;
    #pragma unroll 4
    for (int q = 0; q < jn; ++q)
        c += (kj[q] > ki) ? 1 : 0;
    cntp[(size_t)blockIdx.y * Nn + i] = c;
}

// pool gather (bf16 in/out) fused with rank finalize + score recompute
__global__ __launch_bounds__(128) void k_gather_pool(
    const unsigned short* __restrict__ Hb, const float* __restrict__ scpart,
    const float* __restrict__ invn,
    const int* __restrict__ cntp, int Nn, int nchunk, int kk,
    int* __restrict__ rank_out, unsigned short* __restrict__ Xb) {
    __shared__ int csum[128];
    __shared__ float ssum[128];
    __shared__ int rsh;
    __shared__ float scsh;
    int i = blockIdx.x;
    int c = 0;
    for (int q = threadIdx.x; q < nchunk; q += 128) c += cntp[(size_t)q * Nn + i];
    float s = (threadIdx.x < 16) ? scpart[(size_t)threadIdx.x * Nn + i] : 0.f;
    csum[threadIdx.x] = c; ssum[threadIdx.x] = s;
    __syncthreads();
    if (threadIdx.x == 0) {
        int t = 0;
        int lim = (nchunk < 128) ? nchunk : 128;
        for (int q = 0; q < lim; ++q) t += csum[q];
        float st = 0.f;
        for (int q = 0; q < 16; ++q) st += ssum[q];
        int r = (t < kk) ? t : -1;
        if (rank_out) rank_out[i] = r;
        rsh = r;
        scsh = tanhf(st * invn[0]);
    }
    __syncthreads();
    int r = rsh;
    if (r < 0) return;
    float sc = scsh;
    int cc = threadIdx.x;
    if (cc < HID / 4) {
        ushort4 u = *(const ushort4*)(Hb + (size_t)i * HID + cc * 4);
        ushort4 o;
        o.x = bf16rn(bf2f(u.x) * sc); o.y = bf16rn(bf2f(u.y) * sc);
        o.z = bf16rn(bf2f(u.z) * sc); o.w = bf16rn(bf2f(u.w) * sc);
        *(ushort4*)(Xb + (size_t)r * HID + cc * 4) = o;
    }
}

// readout phase A over bf16 rows: per-slab column max+sum, no atomics
__global__ __launch_bounds__(256) void k_readout_slab(
    const unsigned short* __restrict__ X, int rows, int rpb,
    float* __restrict__ pmax, float* __restrict__ psum) {
    __shared__ float4 lmx[4][64];
    __shared__ float4 lsm[4][64];
    int lane = threadIdx.x & 63;
    int rgrp = threadIdx.x >> 6;
    int c4 = blockIdx.x * 64 + lane;
    int r0 = blockIdx.y * rpb;
    int r1 = min(rows, r0 + rpb);
    float4 mx = make_float4(-INFINITY, -INFINITY, -INFINITY, -INFINITY);
    float4 sm = make_float4(0.f, 0.f, 0.f, 0.f);
    if (c4 < HID / 4) {
        for (int r = r0 + rgrp; r < r1; r += 4) {
            ushort4 u = *(const ushort4*)(X + (size_t)r * HID + c4 * 4);
            float vx = bf2f(u.x), vy = bf2f(u.y), vz = bf2f(u.z), vw = bf2f(u.w);
            mx.x = fmaxf(mx.x, vx); mx.y = fmaxf(mx.y, vy);
            mx.z = fmaxf(mx.z, vz); mx.w = fmaxf(mx.w, vw);
            sm.x += vx; sm.y += vy; sm.z += vz; sm.w += vw;
        }
    }
    lmx[rgrp][lane] = mx; lsm[rgrp][lane] = sm;
    __syncthreads();
    if (rgrp == 0 && c4 < HID / 4) {
        #pragma unroll
        for (int g = 1; g < 4; ++g) {
            float4 m2 = lmx[g][lane], s2 = lsm[g][lane];
            mx.x = fmaxf(mx.x, m2.x); mx.y = fmaxf(mx.y, m2.y);
            mx.z = fmaxf(mx.z, m2.z); mx.w = fmaxf(mx.w, m2.w);
            sm.x += s2.x; sm.y += s2.y; sm.z += s2.z; sm.w += s2.w;
        }
        *(float4*)(pmax + (size_t)blockIdx.y * HID + c4 * 4) = mx;
        *(float4*)(psum + (size_t)blockIdx.y * HID + c4 * 4) = sm;
    }
}

// fold both pools' slabs -> z[1000]
__global__ __launch_bounds__(64) void k_combine_all(
    const float* __restrict__ pm1, const float* __restrict__ ps1, int ns1,
    const float* __restrict__ pm2, const float* __restrict__ ps2, int ns2,
    float* __restrict__ z) {
    int j = blockIdx.x * 64 + threadIdx.x;
    if (j >= HID) return;
    float m1 = -INFINITY, s1 = 0.f;
    for (int s = 0; s < ns1; ++s) {
        m1 = fmaxf(m1, pm1[(size_t)s * HID + j]);
        s1 += ps1[(size_t)s * HID + j];
    }
    float m2 = -INFINITY, s2 = 0.f;
    for (int s = 0; s < ns2; ++s) {
        m2 = fmaxf(m2, pm2[(size_t)s * HID + j]);
        s2 += ps2[(size_t)s * HID + j];
    }
    z[j] = m1 + m2;
    z[HID + j] = s1 * (1.0f / (float)K1) + s2 * (1.0f / (float)K2);
}

__global__ __launch_bounds__(256) void k_mv(
    const float* __restrict__ v, const float* __restrict__ W,
    const float* __restrict__ bias, float* __restrict__ y,
    int rowsN, int K, int act) {
    int wave = (blockIdx.x * 256 + threadIdx.x) >> 6;
    int lane = threadIdx.x & 63;
    if (wave >= rowsN) return;
    const float* wr = W + (size_t)wave * K;
    float s = 0.f;
    for (int c = lane * 4; c < K; c += 256) {
        float4 a = *(const float4*)(wr + c);
        float4 xv = *(const float4*)(v + c);
        s += a.x * xv.x + a.y * xv.y + a.z * xv.z + a.w * xv.w;
    }
    for (int off = 32; off > 0; off >>= 1) s += __shfl_down(s, off, 64);
    if (lane == 0) {
        float r = s + bias[wave];
        y[wave] = (act == 0) ? fmaxf(r, 0.f) : 1.f / (1.f + expf(-r));
    }
}

// ---------------- launch ----------------
extern "C" void kernel_launch(void* const* d_in, const int* in_sizes, int n_in,
                              void* d_out, int out_size, void* d_ws, size_t ws_size,
                              hipStream_t stream) {
    const float* x      = (const float*)d_in[0];
    const int*   esrc   = (const int*)d_in[1];
    const int*   edst   = (const int*)d_in[2];
    const float* ew     = (const float*)d_in[3];
    const float* W1_rel = (const float*)d_in[4];
    const float* b1     = (const float*)d_in[5];
    const float* W1_root= (const float*)d_in[6];
    const float* p1     = (const float*)d_in[7];
    const float* W2_rel = (const float*)d_in[8];
    const float* b2     = (const float*)d_in[9];
    const float* W2_root= (const float*)d_in[10];
    const float* p2     = (const float*)d_in[11];
    const float* l1W    = (const float*)d_in[12];
    const float* l1b    = (const float*)d_in[13];
    const float* l2W    = (const float*)d_in[14];
    const float* l2b    = (const float*)d_in[15];
    const float* l3W    = (const float*)d_in[16];
    const float* l3b    = (const float*)d_in[17];
    float* out = (float*)d_out;
    float* ws  = (float*)d_ws;

    if (ws_size < (size_t)WS_FLOATS * sizeof(float)) return;

    int*            offs  = (int*)(ws + CSR_OFFS);
    int*            pos   = (int*)(ws + CSR_POS);
    int2*           ce    = (int2*)(ws + CSR_EDGE);
    unsigned short* aggb  = (unsigned short*)(ws + OFF_AGG);
    unsigned short* hb    = (unsigned short*)(ws + OFF_H);
    unsigned short* xp2b  = (unsigned short*)(ws + OFF_XP2);
    float*          scp   = ws + OFF_SCP;
    int*            rk1   = (int*)(ws + OFF_RK1);
    float*          zbuf  = ws + OFF_Z;
    float*          t1    = ws + OFF_T1;
    float*          t2    = ws + OFF_T2;
    float*          invn  = ws + OFF_INV;
    int*            cntp  = (int*)(ws + OFF_CNT);
    float*          pm1   = ws + OFF_PM1;
    float*          ps1   = ws + OFF_PS1;
    float*          pm2   = ws + OFF_PM2;
    float*          ps2   = ws + OFF_PS2;
    unsigned short* xb    = (unsigned short*)(ws + OFF_XB);
    unsigned short* w1rb  = (unsigned short*)(ws + OFF_W1RB);
    unsigned short* w1tb  = (unsigned short*)(ws + OFF_W1TB);
    unsigned short* w2rb  = (unsigned short*)(ws + OFF_W2RB);
    unsigned short* w2tb  = (unsigned short*)(ws + OFF_W2TB);
    unsigned short* xp1b  = (unsigned short*)(ws + OFF_XP1B);

    hipMemsetAsync(pos, 0, NN1 * sizeof(int), stream);
    k_prep<<<dim3(2500, 7), 256, 0, stream>>>(
        x, xb, W1_rel, w1rb, W1_root, w1tb, W2_rel, w2rb, W2_root, w2tb,
        p1, p2, invn, edst, pos);
    k_scan<<<1, 1024, 0, stream>>>(pos, offs);
    k_fill<<<(NE + 255) / 256, 256, 0, stream>>>(esrc, edst, ew, pos, ce);

    // conv1 (+fused score partials vs p1)
    k_gather1<<<(NN1 * 64 + 255) / 256, 256, 0, stream>>>(xb, offs, ce, aggb);
    {
        int nby = (NN1 + 63) / 64;
        int nblk = 64 * ((nby + 7) / 8);
        k_gemm_bf16<<<nblk, 256, 0, stream>>>(
            aggb, w1rb, xb, w1tb, b1, p1, hb, scp, NN1, HID, FIN, FIN, nby);
    }

    // pool1
    k_rank_partial<<<dim3((NN1 + 255) / 256, NN1 / RCHUNK), 256, 0, stream>>>(scp, cntp, NN1);
    k_gather_pool<<<NN1, 128, 0, stream>>>(hb, scp, invn + 0, cntp, NN1, NN1 / RCHUNK, K1,
                                           rk1, xp1b);
    k_readout_slab<<<dim3(2, ROSLAB1), 256, 0, stream>>>(xp1b, K1, RORPB, pm1, ps1);

    // conv2 (+fused score partials vs p2)
    k_gather2<<<(NN1 * 64 + 255) / 256, 256, 0, stream>>>(xp1b, offs, ce, rk1, aggb);
    {
        int nby = (NN2 + 63) / 64;
        int nblk = 64 * ((nby + 7) / 8);
        k_gemm_bf16<<<nblk, 256, 0, stream>>>(
            aggb, w2rb, xp1b, w2tb, b2, p2, hb, scp, NN2, HID, HID, HID, nby);
    }

    // pool2 + combine
    k_rank_partial<<<dim3((NN2 + 255) / 256, NN2 / RCHUNK), 256, 0, stream>>>(scp, cntp, NN2);
    k_gather_pool<<<NN2, 128, 0, stream>>>(hb, scp, invn + 1, cntp, NN2, NN2 / RCHUNK, K2,
                                           (int*)nullptr, xp2b);
    k_readout_slab<<<dim3(2, ROSLAB2), 256, 0, stream>>>(xp2b, K2, RORPB, pm2, ps2);
    k_combine_all<<<(HID + 63) / 64, 64, 0, stream>>>(pm1, ps1, ROSLAB1, pm2, ps2, ROSLAB2, zbuf);

    // MLP
    k_mv<<<(2000 * 64) / 256, 256, 0, stream>>>(zbuf, l1W, l1b, t1, 2000, 1000, 0);
    k_mv<<<(4000 * 64) / 256, 256, 0, stream>>>(t1, l2W, l2b, t2, 4000, 2000, 0);
    k_mv<<<(100 * 64) / 256, 256, 0, stream>>>(t2, l3W, l3b, out, 100, 4000, 1);
}